// Round 4
// baseline (573.581 us; speedup 1.0000x reference)
//
#include <hip/hip_runtime.h>
#include <hip/hip_bf16.h>
#include <math.h>

// Problem constants
#define SEQ 2048
#define DIM 4096
#define NH 32
#define NKV 8
#define HD 128
#define KVD 1024              // NKV*HD
#define SCALE 0.08838834764831845f
#define NEGBIG -1000000000.0f

typedef __bf16 bf16;
typedef __attribute__((ext_vector_type(2))) __bf16 bf16x2;
typedef __attribute__((ext_vector_type(4))) __bf16 bf16x4;
typedef __attribute__((ext_vector_type(8))) __bf16 bf16x8;
typedef __attribute__((ext_vector_type(4))) float f32x4;

// ---------------------------------------------------------------------------
// async global->LDS 16B copy (wave-uniform LDS base + lane*16 semantics)
__device__ __forceinline__ void async_g2l16(const void* g, void* l) {
  __builtin_amdgcn_global_load_lds(
      (const __attribute__((address_space(1))) void*)g,
      (__attribute__((address_space(3))) void*)l,
      16, 0, 0);
}

// ---------------------------------------------------------------------------
// B^T GEMM core, 128x128 tile, BK=32, 256 threads.
//  - B is ALWAYS fp32 (weights consumed directly; cast fused into frag read).
//    fp32 LDS tile [128 rows x 32 k], row=128B=8 16B-groups, stored with
//    group ^= (row&7) (swizzle applied on GLOBAL source address; LDS dest is
//    wave-uniform-contiguous as global_load_lds requires). Fragment read =
//    two independent ds_read_b128 at positions (2q)^(row&7), (2q+1)^(row&7)
//    -> 2 lanes/bank-quad per 16-lane phase = conflict-free. cvt->bf16 in reg.
//  - A is fp32 (qkv: x) or bf16 (out: attnb, R3-proven swizzled path).
template<typename TA>
__device__ __forceinline__ void gemm_core(
    const TA* __restrict__ A, int lda,
    const float* __restrict__ B, int ldb,
    int K, int mBase, f32x4 acc[4][4])
{
  constexpr bool AF32 = (sizeof(TA) == 4);
  __shared__ __align__(16) TA    As[128 * 32];
  __shared__ __align__(16) float Bs[128 * 32];

  const int tid  = threadIdx.x;
  const int lane = tid & 63;
  const int w    = tid >> 6;
  const int l15  = lane & 15;
  const int quad = lane >> 4;
  const int wr   = (w >> 1) * 64;
  const int wc   = (w & 1) * 64;

  // fp32 staging pattern: op t covers rows w*32+t*8 .. +8
  const int r8 = lane >> 3;                 // row within 8-row chunk
  const int gsw = (lane & 7) ^ r8;          // swizzled 16B-group (4 fp32)

  // bf16 A staging pattern (R3): 2 ops of 16 rows
  const int srow = lane >> 2;
  const int kswz = ((lane & 3) ^ ((srow >> 1) & 3)) * 8;

  const f32x4 vzero = {0.f, 0.f, 0.f, 0.f};
#pragma unroll
  for (int mi = 0; mi < 4; ++mi)
#pragma unroll
    for (int ni = 0; ni < 4; ++ni) acc[mi][ni] = vzero;

  const int rsw = ((l15 >> 1) & 3);         // bf16 read-side swizzle

  for (int k0 = 0; k0 < K; k0 += 32) {
    __syncthreads();
    // ---- stage A
    if constexpr (AF32) {
#pragma unroll
      for (int t = 0; t < 4; ++t) {
        int row = w * 32 + t * 8 + r8;
        async_g2l16((const float*)A + (size_t)(mBase + row) * lda + k0 + gsw * 4,
                    As + (w * 32 + t * 8) * 32);
      }
    } else {
      async_g2l16((const bf16*)A + (size_t)(mBase + w * 16 + srow) * lda + k0 + kswz,
                  As + w * 512);
      async_g2l16((const bf16*)A + (size_t)(mBase + 64 + w * 16 + srow) * lda + k0 + kswz,
                  As + (w + 4) * 512);
    }
    // ---- stage B (fp32)
#pragma unroll
    for (int t = 0; t < 4; ++t) {
      int row = w * 32 + t * 8 + r8;
      async_g2l16(B + (size_t)row * ldb + k0 + gsw * 4,
                  Bs + (w * 32 + t * 8) * 32);
    }
    __syncthreads();

    // ---- fragments
    bf16x8 a[4], b[4];
#pragma unroll
    for (int mi = 0; mi < 4; ++mi) {
      int row = wr + mi * 16 + l15;
      if constexpr (AF32) {
        const float* rp = (const float*)As + row * 32;
        int p0 = (2 * quad) ^ (row & 7);
        f32x4 lo = *(const f32x4*)(rp + p0 * 4);
        f32x4 hi = *(const f32x4*)(rp + (p0 ^ 1) * 4);
        bf16x8 f;
#pragma unroll
        for (int j = 0; j < 4; ++j) { f[j] = (bf16)lo[j]; f[4 + j] = (bf16)hi[j]; }
        a[mi] = f;
      } else {
        a[mi] = *(const bf16x8*)((const bf16*)As + row * 32 + ((quad ^ rsw) * 8));
      }
    }
#pragma unroll
    for (int ni = 0; ni < 4; ++ni) {
      int row = wc + ni * 16 + l15;
      const float* rp = Bs + row * 32;
      int p0 = (2 * quad) ^ (row & 7);
      f32x4 lo = *(const f32x4*)(rp + p0 * 4);
      f32x4 hi = *(const f32x4*)(rp + (p0 ^ 1) * 4);
      bf16x8 f;
#pragma unroll
      for (int j = 0; j < 4; ++j) { f[j] = (bf16)lo[j]; f[4 + j] = (bf16)hi[j]; }
      b[ni] = f;
    }
#pragma unroll
    for (int mi = 0; mi < 4; ++mi)
#pragma unroll
      for (int ni = 0; ni < 4; ++ni)
        acc[mi][ni] = __builtin_amdgcn_mfma_f32_16x16x32_bf16(
            a[mi], b[ni], acc[mi][ni], 0, 0, 0);
  }
}

// ---------------------------------------------------------------------------
// QKV projection from fp32 x / fp32 weights, fused RoPE/scale/cast/V-transpose.
__global__ __launch_bounds__(256, 2) void qkv_gemm_kernel(
    const float* __restrict__ x, const float* __restrict__ wq,
    const float* __restrict__ wk, const float* __restrict__ wv,
    const float* __restrict__ fc, const float* __restrict__ fs,
    bf16* __restrict__ Qb, bf16* __restrict__ Kb, bf16* __restrict__ Vt)
{
  const int nb = blockIdx.x;
  const int mBase = blockIdx.y * 128;
  const float* Bm;
  if (nb < 32)      Bm = wq + (size_t)nb * 128 * DIM;
  else if (nb < 40) Bm = wk + (size_t)(nb - 32) * 128 * DIM;
  else              Bm = wv + (size_t)(nb - 40) * 128 * DIM;

  f32x4 acc[4][4];
  gemm_core<float>(x, DIM, Bm, DIM, DIM, mBase, acc);

  const int tid  = threadIdx.x;
  const int lane = tid & 63;
  const int w    = tid >> 6;
  const int l15  = lane & 15;
  const int quad = lane >> 4;
  const int wr   = (w >> 1) * 64;
  const int wc   = (w & 1) * 64;

  if (nb < 40) {
    // RoPE: d and d^1 live in adjacent lanes (l15 bit0) -> shfl_xor(1)
    const bool isQ = (nb < 32);
    bf16* dst = isQ ? (Qb + nb * HD) : (Kb + (nb - 32) * HD);
    const int ldd = isQ ? DIM : KVD;
    const float sc = isQ ? SCALE : 1.0f;
    const int odd = l15 & 1;
#pragma unroll
    for (int mi = 0; mi < 4; ++mi) {
#pragma unroll
      for (int ni = 0; ni < 4; ++ni) {
        int d = wc + ni * 16 + l15;
        int fidx = d >> 1;
#pragma unroll
        for (int r = 0; r < 4; ++r) {
          int s = mBase + wr + mi * 16 + quad * 4 + r;
          float v  = acc[mi][ni][r];
          float pv = __shfl_xor(v, 1, 64);
          float c  = fc[s * 64 + fidx];
          float sn = fs[s * 64 + fidx];
          float o  = odd ? (pv * sn + v * c) : (v * c - pv * sn);
          dst[(size_t)s * ldd + d] = (bf16)(o * sc);
        }
      }
    }
  } else {
    // V: transpose to [kv][d][s]; 4 consecutive rows (s) -> bf16x4 store
    const int t = nb - 40;
#pragma unroll
    for (int mi = 0; mi < 4; ++mi) {
      int srow = mBase + wr + mi * 16 + quad * 4;
#pragma unroll
      for (int ni = 0; ni < 4; ++ni) {
        int d = wc + ni * 16 + l15;
        bf16x4 pv;
#pragma unroll
        for (int r = 0; r < 4; ++r) pv[r] = (bf16)acc[mi][ni][r];
        *(bf16x4*)(Vt + ((size_t)t * HD + d) * SEQ + srow) = pv;
      }
    }
  }
}

// Output projection: attn(2048x4096 bf16) @ wo^T(fp32) -> out (fp32)
__global__ __launch_bounds__(256, 2) void out_gemm_kernel(
    const bf16* __restrict__ attnb, const float* __restrict__ wo,
    float* __restrict__ out)
{
  const int mBase = blockIdx.y * 128;
  f32x4 acc[4][4];
  gemm_core<bf16>(attnb, DIM, wo + (size_t)blockIdx.x * 128 * DIM, DIM, DIM,
                  mBase, acc);

  const int tid  = threadIdx.x;
  const int lane = tid & 63;
  const int w    = tid >> 6;
  const int l15  = lane & 15;
  const int quad = lane >> 4;
  const int wr   = (w >> 1) * 64;
  const int wc   = (w & 1) * 64;
#pragma unroll
  for (int mi = 0; mi < 4; ++mi) {
    int row = mBase + wr + mi * 16 + quad * 4;
#pragma unroll
    for (int ni = 0; ni < 4; ++ni) {
      int col = blockIdx.x * 128 + wc + ni * 16 + l15;
#pragma unroll
      for (int r = 0; r < 4; ++r)
        out[(size_t)(row + r) * DIM + col] = acc[mi][ni][r];
    }
  }
}

// ---------------------------------------------------------------------------
// Flash attention: transposed scores (St = K @ Q^T). Unchanged from R3.
__global__ __launch_bounds__(256, 2) void attn_kernel(
    const bf16* __restrict__ Qb, const bf16* __restrict__ Kb,
    const bf16* __restrict__ Vt, bf16* __restrict__ attnb)
{
  __shared__ __align__(16) bf16 Ks[64 * 128];   // [key][hd], swizzled 16B grps
  __shared__ __align__(16) bf16 Vs[128 * 64];   // [hd][key], swizzled
  __shared__ __align__(16) bf16 Ps[128 * 64];   // [query][key], swizzled

  const int b    = blockIdx.x;
  const int half = b >> 8;
  const int r8   = b & 255;
  const int h    = (half << 4) | (r8 >> 4);
  const int qt   = half ? (r8 & 15) : 15 - (r8 & 15);
  const int kvh  = h >> 2;
  const int qbase = qt * 128;

  const int tid  = threadIdx.x;
  const int lane = tid & 63;
  const int w    = tid >> 6;
  const int l15  = lane & 15;
  const int quad = lane >> 4;

  bf16x8 qfrag[2][4];
#pragma unroll
  for (int n = 0; n < 2; ++n) {
    int q = qbase + w * 32 + n * 16 + l15;
#pragma unroll
    for (int ks = 0; ks < 4; ++ks)
      qfrag[n][ks] = *(const bf16x8*)(Qb + (size_t)q * DIM + h * HD +
                                      ks * 32 + quad * 8);
  }

  const f32x4 vzero = {0.f, 0.f, 0.f, 0.f};
  f32x4 oacc[8][2];
#pragma unroll
  for (int dm = 0; dm < 8; ++dm)
#pragma unroll
    for (int n = 0; n < 2; ++n) oacc[dm][n] = vzero;
  float m_run[2] = {-1e30f, -1e30f};
  float l_run[2] = {0.f, 0.f};

  const int nkt = 2 * (qt + 1);
  for (int kt = 0; kt < nkt; ++kt) {
    const int kbase = kt * 64;

    __syncthreads();
#pragma unroll
    for (int t = 0; t < 4; ++t) {
      int kr0 = w * 16 + t * 4;
      int krow = kr0 + (lane >> 4);
      int kg = (lane & 15) ^ (krow & 7);
      async_g2l16(Kb + (size_t)(kbase + krow) * KVD + kvh * HD + kg * 8,
                  Ks + kr0 * 128);
      int vr0 = w * 32 + t * 8;
      int d = vr0 + (lane >> 3);
      int vg = (lane & 7) ^ (d & 7);
      async_g2l16(Vt + ((size_t)kvh * HD + d) * SEQ + kbase + vg * 8,
                  Vs + vr0 * 64);
    }
    __syncthreads();

    f32x4 sacc[4][2];
#pragma unroll
    for (int kg = 0; kg < 4; ++kg)
#pragma unroll
      for (int n = 0; n < 2; ++n) sacc[kg][n] = vzero;
#pragma unroll
    for (int kg = 0; kg < 4; ++kg) {
      bf16x8 kf[4];
#pragma unroll
      for (int ks = 0; ks < 4; ++ks) {
        int row = kg * 16 + l15;
        kf[ks] = *(const bf16x8*)(Ks + row * 128 +
                                  (((ks * 4 + quad) ^ (row & 7)) * 8));
      }
#pragma unroll
      for (int n = 0; n < 2; ++n)
#pragma unroll
        for (int ks = 0; ks < 4; ++ks)
          sacc[kg][n] = __builtin_amdgcn_mfma_f32_16x16x32_bf16(
              kf[ks], qfrag[n][ks], sacc[kg][n], 0, 0, 0);
    }

#pragma unroll
    for (int n = 0; n < 2; ++n) {
      const int qloc = w * 32 + n * 16 + l15;
      const int qglob = qbase + qloc;
      if (kbase + 63 > qbase + w * 32 + n * 16) {
#pragma unroll
        for (int kg = 0; kg < 4; ++kg)
#pragma unroll
          for (int r = 0; r < 4; ++r) {
            int key = kbase + kg * 16 + quad * 4 + r;
            if (key > qglob) sacc[kg][n][r] = NEGBIG;
          }
      }
      float mx = -1e30f;
#pragma unroll
      for (int kg = 0; kg < 4; ++kg)
#pragma unroll
        for (int r = 0; r < 4; ++r) mx = fmaxf(mx, sacc[kg][n][r]);
      mx = fmaxf(mx, __shfl_xor(mx, 16, 64));
      mx = fmaxf(mx, __shfl_xor(mx, 32, 64));
      float mnew = fmaxf(m_run[n], mx);
      float alpha = __expf(m_run[n] - mnew);
      m_run[n] = mnew;
      float rs = 0.f;
#pragma unroll
      for (int kg = 0; kg < 4; ++kg) {
        bf16x4 pk;
#pragma unroll
        for (int r = 0; r < 4; ++r) {
          float p = __expf(sacc[kg][n][r] - mnew);
          rs += p;
          pk[r] = (bf16)p;
        }
        int g16 = (kg * 2 + (quad >> 1)) ^ (qloc & 7);
        *(bf16x4*)(Ps + qloc * 64 + g16 * 8 + (quad & 1) * 4) = pk;
      }
      rs += __shfl_xor(rs, 16, 64);
      rs += __shfl_xor(rs, 32, 64);
      l_run[n] = alpha * l_run[n] + rs;
#pragma unroll
      for (int dm = 0; dm < 8; ++dm)
#pragma unroll
        for (int r = 0; r < 4; ++r) oacc[dm][n][r] *= alpha;
    }

    bf16x8 pf[2][2];
#pragma unroll
    for (int kk = 0; kk < 2; ++kk)
#pragma unroll
      for (int n = 0; n < 2; ++n) {
        int qloc = w * 32 + n * 16 + l15;
        pf[kk][n] = *(const bf16x8*)(Ps + qloc * 64 +
                                     (((kk * 4 + quad) ^ (qloc & 7)) * 8));
      }
#pragma unroll
    for (int dm = 0; dm < 8; ++dm) {
#pragma unroll
      for (int kk = 0; kk < 2; ++kk) {
        int d = dm * 16 + l15;
        bf16x8 vf = *(const bf16x8*)(Vs + d * 64 +
                                     (((kk * 4 + quad) ^ (d & 7)) * 8));
#pragma unroll
        for (int n = 0; n < 2; ++n)
          oacc[dm][n] = __builtin_amdgcn_mfma_f32_16x16x32_bf16(
              vf, pf[kk][n], oacc[dm][n], 0, 0, 0);
      }
    }
  }

#pragma unroll
  for (int n = 0; n < 2; ++n) {
    float inv = 1.0f / l_run[n];
    int q = qbase + w * 32 + n * 16 + l15;
#pragma unroll
    for (int dm = 0; dm < 8; ++dm) {
      bf16x4 ov;
#pragma unroll
      for (int r = 0; r < 4; ++r) ov[r] = (bf16)(oacc[dm][n][r] * inv);
      *(bf16x4*)(attnb + (size_t)q * DIM + h * HD + dm * 16 + quad * 4) = ov;
    }
  }
}

// ---------------------------------------------------------------------------
extern "C" void kernel_launch(void* const* d_in, const int* in_sizes, int n_in,
                              void* d_out, int out_size, void* d_ws, size_t ws_size,
                              hipStream_t stream) {
  const float* x  = (const float*)d_in[0];
  const float* wq = (const float*)d_in[1];
  const float* wk = (const float*)d_in[2];
  const float* wv = (const float*)d_in[3];
  const float* wo = (const float*)d_in[4];
  const float* fc = (const float*)d_in[5];
  const float* fs = (const float*)d_in[6];
  float* out = (float*)d_out;

  size_t off = 0;
  char* wsb = (char*)d_ws;
  auto take = [&](size_t bytes) -> void* {
    void* p = wsb + off;
    off += (bytes + 255) & ~(size_t)255;
    return p;
  };
  bf16*  Qb    = (bf16*)take((size_t)SEQ * DIM * 2);
  bf16*  Kb    = (bf16*)take((size_t)SEQ * KVD * 2);
  bf16*  Vt    = (bf16*)take((size_t)NKV * HD * SEQ * 2);
  bf16*  attnb = (bf16*)take((size_t)SEQ * DIM * 2);

  // fused QKV projection + RoPE/scale/V-transpose epilogue (fp32 in, bf16 out)
  qkv_gemm_kernel<<<dim3(48, 16), 256, 0, stream>>>(x, wq, wk, wv,
                                                    fc, fs, Qb, Kb, Vt);

  // flash attention (512 linear blocks, big/small qt pairing)
  attn_kernel<<<dim3(512), 256, 0, stream>>>(Qb, Kb, Vt, attnb);

  // output projection
  out_gemm_kernel<<<dim3(32, 16), 256, 0, stream>>>(attnb, wo, out);
}

// Round 5
// 499.783 us; speedup vs baseline: 1.1477x; 1.1477x over previous
//
#include <hip/hip_runtime.h>
#include <hip/hip_bf16.h>
#include <math.h>

// Problem constants
#define SEQ 2048
#define DIM 4096
#define NH 32
#define NKV 8
#define HD 128
#define KVD 1024              // NKV*HD
#define SCALE 0.08838834764831845f
#define NEGBIG -1000000000.0f

typedef __bf16 bf16;
typedef __attribute__((ext_vector_type(2))) __bf16 bf16x2;
typedef __attribute__((ext_vector_type(4))) __bf16 bf16x4;
typedef __attribute__((ext_vector_type(8))) __bf16 bf16x8;
typedef __attribute__((ext_vector_type(4))) float f32x4;

// ---------------------------------------------------------------------------
// async global->LDS 16B copy (wave-uniform LDS base + lane*16 semantics)
__device__ __forceinline__ void async_g2l16(const void* g, void* l) {
  __builtin_amdgcn_global_load_lds(
      (const __attribute__((address_space(1))) void*)g,
      (__attribute__((address_space(3))) void*)l,
      16, 0, 0);
}

// ---------------------------------------------------------------------------
// fused fp32 -> bf16 cast for all 5 tensors, float4 vectorized, 1 launch
#define SEG_X  2097152            // SEQ*DIM/4
#define SEG_WQ 4194304            // DIM*DIM/4
#define SEG_WK 1048576            // KVD*DIM/4
#define C0 SEG_X
#define C1 (C0 + SEG_WQ)
#define C2 (C1 + SEG_WK)
#define C3 (C2 + SEG_WK)
#define C4 (C3 + SEG_WQ)          // 12582912 total float4

__global__ void cast_all_kernel(const float* __restrict__ x,
                                const float* __restrict__ wq,
                                const float* __restrict__ wk,
                                const float* __restrict__ wv,
                                const float* __restrict__ wo,
                                bf16* __restrict__ xb, bf16* __restrict__ wqb,
                                bf16* __restrict__ wkb, bf16* __restrict__ wvb,
                                bf16* __restrict__ wob) {
  int i = blockIdx.x * 256 + threadIdx.x;
  const float* src; bf16* dst; int j;
  if (i < C0)      { src = x;  dst = xb;  j = i; }
  else if (i < C1) { src = wq; dst = wqb; j = i - C0; }
  else if (i < C2) { src = wk; dst = wkb; j = i - C1; }
  else if (i < C3) { src = wv; dst = wvb; j = i - C2; }
  else             { src = wo; dst = wob; j = i - C3; }
  float4 v = ((const float4*)src)[j];
  bf16x4 o;
  o[0] = (bf16)v.x; o[1] = (bf16)v.y; o[2] = (bf16)v.z; o[3] = (bf16)v.w;
  ((bf16x4*)dst)[j] = o;
}

// ---------------------------------------------------------------------------
// m97-style B^T GEMM core with XOR-swizzled LDS (conflict-free b128 reads):
// LDS[row][g] holds global k-group g ^ ((row>>1)&3). Swizzle applied on the
// GLOBAL source address at staging (wave-uniform LDS dest preserved), undone
// at fragment read (involution). R3-verified: SQ_LDS_BANK_CONFLICT == 0.
__device__ __forceinline__ void gemm_core(
    const bf16* __restrict__ A, int lda,
    const bf16* __restrict__ B, int ldb,
    int K, int mBase, f32x4 acc[4][4])
{
  __shared__ __align__(16) bf16 As[128 * 32];
  __shared__ __align__(16) bf16 Bs[128 * 32];

  const int tid  = threadIdx.x;
  const int lane = tid & 63;
  const int w    = tid >> 6;
  const int l15  = lane & 15;
  const int quad = lane >> 4;
  const int wr   = (w >> 1) * 64;
  const int wc   = (w & 1) * 64;

  const int srow = lane >> 2;                      // 0..15 within chunk
  const int kswz = ((lane & 3) ^ ((srow >> 1) & 3)) * 8;  // swizzled k-group
  const bf16* gA0 = A + (size_t)(mBase + w * 16 + srow) * lda + kswz;
  const bf16* gA1 = gA0 + (size_t)64 * lda;
  const bf16* gB0 = B + (size_t)(w * 16 + srow) * ldb + kswz;
  const bf16* gB1 = gB0 + (size_t)64 * ldb;
  bf16* lA0 = As + w * 512;
  bf16* lA1 = As + (w + 4) * 512;
  bf16* lB0 = Bs + w * 512;
  bf16* lB1 = Bs + (w + 4) * 512;

  const f32x4 vzero = {0.f, 0.f, 0.f, 0.f};
#pragma unroll
  for (int mi = 0; mi < 4; ++mi)
#pragma unroll
    for (int ni = 0; ni < 4; ++ni) acc[mi][ni] = vzero;

  const int rsw = ((l15 >> 1) & 3);                // read-side swizzle term

  for (int k0 = 0; k0 < K; k0 += 32) {
    __syncthreads();
    async_g2l16(gA0 + k0, lA0);
    async_g2l16(gA1 + k0, lA1);
    async_g2l16(gB0 + k0, lB0);
    async_g2l16(gB1 + k0, lB1);
    __syncthreads();

    bf16x8 a[4], b[4];
#pragma unroll
    for (int mi = 0; mi < 4; ++mi)
      a[mi] = *(const bf16x8*)(As + (wr + mi * 16 + l15) * 32 +
                               ((quad ^ rsw) * 8));
#pragma unroll
    for (int ni = 0; ni < 4; ++ni)
      b[ni] = *(const bf16x8*)(Bs + (wc + ni * 16 + l15) * 32 +
                               ((quad ^ rsw) * 8));
#pragma unroll
    for (int mi = 0; mi < 4; ++mi)
#pragma unroll
      for (int ni = 0; ni < 4; ++ni)
        acc[mi][ni] = __builtin_amdgcn_mfma_f32_16x16x32_bf16(
            a[mi], b[ni], acc[mi][ni], 0, 0, 0);
  }
}

// ---------------------------------------------------------------------------
// QKV projection with fused RoPE/scale/cast/V-transpose epilogue.
__global__ __launch_bounds__(256, 2) void qkv_gemm_kernel(
    const bf16* __restrict__ xb, const bf16* __restrict__ wqb,
    const bf16* __restrict__ wkb, const bf16* __restrict__ wvb,
    const float* __restrict__ fc, const float* __restrict__ fs,
    bf16* __restrict__ Qb, bf16* __restrict__ Kb, bf16* __restrict__ Vt)
{
  const int nb = blockIdx.x;
  const int mBase = blockIdx.y * 128;
  const bf16* Bm;
  if (nb < 32)      Bm = wqb + (size_t)nb * 128 * DIM;
  else if (nb < 40) Bm = wkb + (size_t)(nb - 32) * 128 * DIM;
  else              Bm = wvb + (size_t)(nb - 40) * 128 * DIM;

  f32x4 acc[4][4];
  gemm_core(xb, DIM, Bm, DIM, DIM, mBase, acc);

  const int tid  = threadIdx.x;
  const int lane = tid & 63;
  const int w    = tid >> 6;
  const int l15  = lane & 15;
  const int quad = lane >> 4;
  const int wr   = (w >> 1) * 64;
  const int wc   = (w & 1) * 64;

  if (nb < 40) {
    // RoPE: d and d^1 live in adjacent lanes (l15 bit0) -> shfl_xor(1)
    const bool isQ = (nb < 32);
    bf16* dst = isQ ? (Qb + nb * HD) : (Kb + (nb - 32) * HD);
    const int ldd = isQ ? DIM : KVD;
    const float sc = isQ ? SCALE : 1.0f;
    const int odd = l15 & 1;
#pragma unroll
    for (int mi = 0; mi < 4; ++mi) {
#pragma unroll
      for (int ni = 0; ni < 4; ++ni) {
        int d = wc + ni * 16 + l15;
        int fidx = d >> 1;
#pragma unroll
        for (int r = 0; r < 4; ++r) {
          int s = mBase + wr + mi * 16 + quad * 4 + r;
          float v  = acc[mi][ni][r];
          float pv = __shfl_xor(v, 1, 64);
          float c  = fc[s * 64 + fidx];
          float sn = fs[s * 64 + fidx];
          float o  = odd ? (pv * sn + v * c) : (v * c - pv * sn);
          dst[(size_t)s * ldd + d] = (bf16)(o * sc);
        }
      }
    }
  } else {
    // V: transpose to [kv][d][s]; 4 consecutive rows (s) -> bf16x4 store
    const int t = nb - 40;
#pragma unroll
    for (int mi = 0; mi < 4; ++mi) {
      int srow = mBase + wr + mi * 16 + quad * 4;
#pragma unroll
      for (int ni = 0; ni < 4; ++ni) {
        int d = wc + ni * 16 + l15;
        bf16x4 pv;
#pragma unroll
        for (int r = 0; r < 4; ++r) pv[r] = (bf16)acc[mi][ni][r];
        *(bf16x4*)(Vt + ((size_t)t * HD + d) * SEQ + srow) = pv;
      }
    }
  }
}

// Output projection: attn(2048x4096 bf16) @ wo^T -> out (fp32)
__global__ __launch_bounds__(256, 2) void out_gemm_kernel(
    const bf16* __restrict__ attnb, const bf16* __restrict__ wob,
    float* __restrict__ out)
{
  const int mBase = blockIdx.y * 128;
  f32x4 acc[4][4];
  gemm_core(attnb, DIM, wob + (size_t)blockIdx.x * 128 * DIM, DIM, DIM,
            mBase, acc);

  const int tid  = threadIdx.x;
  const int lane = tid & 63;
  const int w    = tid >> 6;
  const int l15  = lane & 15;
  const int quad = lane >> 4;
  const int wr   = (w >> 1) * 64;
  const int wc   = (w & 1) * 64;
#pragma unroll
  for (int mi = 0; mi < 4; ++mi) {
    int row = mBase + wr + mi * 16 + quad * 4;
#pragma unroll
    for (int ni = 0; ni < 4; ++ni) {
      int col = blockIdx.x * 128 + wc + ni * 16 + l15;
#pragma unroll
      for (int r = 0; r < 4; ++r)
        out[(size_t)(row + r) * DIM + col] = acc[mi][ni][r];
    }
  }
}

// ---------------------------------------------------------------------------
// Flash attention v3: transposed scores, 64-query tiles for occupancy.
//  - block = (head h, 64-query tile qt); wave w owns queries [qt*64+w*16, +16)
//  - Q frags + softmax m/l in registers; P wave-private in LDS (swizzled)
//  - LDS = 40 KB (Ks 16 + Vs 16 + Ps 8); VGPR ~130 -> 3 blocks/CU
//  - 1024 blocks so the extra occupancy slots are filled
__global__ __launch_bounds__(256, 3) void attn_kernel(
    const bf16* __restrict__ Qb, const bf16* __restrict__ Kb,
    const bf16* __restrict__ Vt, bf16* __restrict__ attnb)
{
  __shared__ __align__(16) bf16 Ks[64 * 128];   // [key][hd], swizzled 16B grps
  __shared__ __align__(16) bf16 Vs[128 * 64];   // [hd][key], swizzled
  __shared__ __align__(16) bf16 Ps[64 * 64];    // [query][key], swizzled

  // grid: 1024 linear blocks; half 0 runs qt heavy-first, half 1 light-first
  const int b    = blockIdx.x;
  const int half = b >> 9;
  const int r    = b & 511;
  const int h    = (half << 4) | (r >> 5);
  const int qt   = half ? (r & 31) : 31 - (r & 31);
  const int kvh  = h >> 2;
  const int qbase = qt * 64;

  const int tid  = threadIdx.x;
  const int lane = tid & 63;
  const int w    = tid >> 6;
  const int l15  = lane & 15;
  const int quad = lane >> 4;
  const int qloc = w * 16 + l15;        // query within tile (wave-private row)
  const int qglob = qbase + qloc;

  // Q fragments in registers (B-operand): lane=query, k=ks*32+quad*8+j
  bf16x8 qfrag[4];
#pragma unroll
  for (int ks = 0; ks < 4; ++ks)
    qfrag[ks] = *(const bf16x8*)(Qb + (size_t)qglob * DIM + h * HD +
                                 ks * 32 + quad * 8);

  const f32x4 vzero = {0.f, 0.f, 0.f, 0.f};
  f32x4 oacc[8];                        // O^T accumulator, [d-tile]
#pragma unroll
  for (int dm = 0; dm < 8; ++dm) oacc[dm] = vzero;
  float m_run = -1e30f, l_run = 0.f;

  const int nkt = qt + 1;               // 64-key steps
  for (int kt = 0; kt < nkt; ++kt) {
    const int kbase = kt * 64;

    __syncthreads();                    // prior iter's Ks/Vs reads complete
#pragma unroll
    for (int t = 0; t < 4; ++t) {
      int kr0 = w * 16 + t * 4;
      int krow = kr0 + (lane >> 4);
      int kg = (lane & 15) ^ (krow & 7);
      async_g2l16(Kb + (size_t)(kbase + krow) * KVD + kvh * HD + kg * 8,
                  Ks + kr0 * 128);
      int vr0 = w * 32 + t * 8;
      int d = vr0 + (lane >> 3);
      int vg = (lane & 7) ^ (d & 7);
      async_g2l16(Vt + ((size_t)kvh * HD + d) * SEQ + kbase + vg * 8,
                  Vs + vr0 * 64);
    }
    __syncthreads();                    // staged (vmcnt(0) drained)

    // St = K @ Q^T : C-frag col=l15=query, row=quad*4+r=key
    f32x4 sacc[4];
#pragma unroll
    for (int kg = 0; kg < 4; ++kg) sacc[kg] = vzero;
#pragma unroll
    for (int kg = 0; kg < 4; ++kg) {
      bf16x8 kf[4];
#pragma unroll
      for (int ks = 0; ks < 4; ++ks) {
        int row = kg * 16 + l15;
        kf[ks] = *(const bf16x8*)(Ks + row * 128 +
                                  (((ks * 4 + quad) ^ (row & 7)) * 8));
      }
#pragma unroll
      for (int ks = 0; ks < 4; ++ks)
        sacc[kg] = __builtin_amdgcn_mfma_f32_16x16x32_bf16(
            kf[ks], qfrag[ks], sacc[kg], 0, 0, 0);
    }

    // causal mask (diagonal iter only)
    if (kt == qt) {
#pragma unroll
      for (int kg = 0; kg < 4; ++kg)
#pragma unroll
        for (int r = 0; r < 4; ++r) {
          int key = kbase + kg * 16 + quad * 4 + r;
          if (key > qglob) sacc[kg][r] = NEGBIG;
        }
    }

    // online softmax per query (register m/l, 2 shuffles per reduce)
    float mx = -1e30f;
#pragma unroll
    for (int kg = 0; kg < 4; ++kg)
#pragma unroll
      for (int r = 0; r < 4; ++r) mx = fmaxf(mx, sacc[kg][r]);
    mx = fmaxf(mx, __shfl_xor(mx, 16, 64));
    mx = fmaxf(mx, __shfl_xor(mx, 32, 64));
    float mnew = fmaxf(m_run, mx);
    float alpha = __expf(m_run - mnew);
    m_run = mnew;
    float rs = 0.f;
#pragma unroll
    for (int kg = 0; kg < 4; ++kg) {
      bf16x4 pk;
#pragma unroll
      for (int r = 0; r < 4; ++r) {
        float p = __expf(sacc[kg][r] - mnew);
        rs += p;
        pk[r] = (bf16)p;
      }
      int g16 = (kg * 2 + (quad >> 1)) ^ (qloc & 7);
      *(bf16x4*)(Ps + qloc * 64 + g16 * 8 + (quad & 1) * 4) = pk;
    }
    rs += __shfl_xor(rs, 16, 64);
    rs += __shfl_xor(rs, 32, 64);
    l_run = alpha * l_run + rs;
#pragma unroll
    for (int dm = 0; dm < 8; ++dm)
#pragma unroll
      for (int r = 0; r < 4; ++r) oacc[dm][r] *= alpha;

    // O^T += V^T @ P^T  (Ps rows are wave-private -> no barrier needed)
    bf16x8 pf[2];
#pragma unroll
    for (int kk = 0; kk < 2; ++kk)
      pf[kk] = *(const bf16x8*)(Ps + qloc * 64 +
                                (((kk * 4 + quad) ^ (qloc & 7)) * 8));
#pragma unroll
    for (int dm = 0; dm < 8; ++dm) {
#pragma unroll
      for (int kk = 0; kk < 2; ++kk) {
        int d = dm * 16 + l15;
        bf16x8 vf = *(const bf16x8*)(Vs + d * 64 +
                                     (((kk * 4 + quad) ^ (d & 7)) * 8));
        oacc[dm] = __builtin_amdgcn_mfma_f32_16x16x32_bf16(
            vf, pf[kk], oacc[dm], 0, 0, 0);
      }
    }
  }

  // epilogue: O^T frag col=l15=query, row=quad*4+r=d -> pack 4 d's per store
  {
    float inv = 1.0f / l_run;
#pragma unroll
    for (int dm = 0; dm < 8; ++dm) {
      bf16x4 ov;
#pragma unroll
      for (int r = 0; r < 4; ++r) ov[r] = (bf16)(oacc[dm][r] * inv);
      *(bf16x4*)(attnb + (size_t)qglob * DIM + h * HD + dm * 16 + quad * 4) = ov;
    }
  }
}

// ---------------------------------------------------------------------------
extern "C" void kernel_launch(void* const* d_in, const int* in_sizes, int n_in,
                              void* d_out, int out_size, void* d_ws, size_t ws_size,
                              hipStream_t stream) {
  const float* x  = (const float*)d_in[0];
  const float* wq = (const float*)d_in[1];
  const float* wk = (const float*)d_in[2];
  const float* wv = (const float*)d_in[3];
  const float* wo = (const float*)d_in[4];
  const float* fc = (const float*)d_in[5];
  const float* fs = (const float*)d_in[6];
  float* out = (float*)d_out;

  size_t off = 0;
  char* wsb = (char*)d_ws;
  auto take = [&](size_t bytes) -> void* {
    void* p = wsb + off;
    off += (bytes + 255) & ~(size_t)255;
    return p;
  };
  bf16*  xb    = (bf16*)take((size_t)SEQ * DIM * 2);
  bf16*  wqb   = (bf16*)take((size_t)DIM * DIM * 2);
  bf16*  wkb   = (bf16*)take((size_t)KVD * DIM * 2);
  bf16*  wvb   = (bf16*)take((size_t)KVD * DIM * 2);
  bf16*  wob   = (bf16*)take((size_t)DIM * DIM * 2);
  bf16*  Qb    = (bf16*)take((size_t)SEQ * DIM * 2);
  bf16*  Kb    = (bf16*)take((size_t)SEQ * KVD * 2);
  bf16*  Vt    = (bf16*)take((size_t)NKV * HD * SEQ * 2);
  bf16*  attnb = (bf16*)take((size_t)SEQ * DIM * 2);

  // fused cast (1 launch)
  cast_all_kernel<<<C4 / 256, 256, 0, stream>>>(x, wq, wk, wv, wo,
                                                xb, wqb, wkb, wvb, wob);

  // fused QKV projection + RoPE/scale/V-transpose epilogue (bf16 outputs)
  qkv_gemm_kernel<<<dim3(48, 16), 256, 0, stream>>>(xb, wqb, wkb, wvb,
                                                    fc, fs, Qb, Kb, Vt);

  // flash attention (1024 linear blocks, 64-query tiles)
  attn_kernel<<<dim3(1024), 256, 0, stream>>>(Qb, Kb, Vt, attnb);

  // output projection
  out_gemm_kernel<<<dim3(32, 16), 256, 0, stream>>>(attnb, wob, out);
}